// Round 6
// baseline (19447.841 us; speedup 1.0000x reference)
//
#include <hip/hip_runtime.h>
#include <hip/hip_bf16.h>
#include <math.h>

typedef unsigned long long u64;

// Sizes
#define N_NODES 8192
#define IN_DIM 64
#define MLP_HID 128
#define EMB 512
#define HID 1024
#define G3 (3*HID)   // 3072
#define SEQ 8192
#define NREP 8       // exchange-ring replication factor (one per XCD)

// ---------------------------------------------------------------------------
// DPP wave64 sum: 6 VALU-latency stages (vs 6 ds_bpermute ~40-60cy each).
// row_shr:1/2/4/8 -> per-16-row sums in lanes 15/31/47/63;
// row_bcast:15 (rows 1,3) -> lane31=rows0+1, lane63=rows2+3;
// row_bcast:31 (rows 2,3) -> lane63=all. readlane(63) -> wave-uniform.
// bound_ctrl=true: invalid src reads 0 (safe for +). All 64 lanes active in
// the compute region (guards are wave-uniform).
// ---------------------------------------------------------------------------
template<int CTRL, int ROW_MASK>
__device__ __forceinline__ float dpp_add(float x) {
    int mv = __builtin_amdgcn_update_dpp(0, __float_as_int(x), CTRL, ROW_MASK, 0xF, true);
    return x + __int_as_float(mv);
}
__device__ __forceinline__ float wave_sum64(float x) {
    x = dpp_add<0x111, 0xF>(x);   // row_shr:1
    x = dpp_add<0x112, 0xF>(x);   // row_shr:2
    x = dpp_add<0x114, 0xF>(x);   // row_shr:4
    x = dpp_add<0x118, 0xF>(x);   // row_shr:8
    x = dpp_add<0x142, 0xA>(x);   // row_bcast:15 -> rows 1,3
    x = dpp_add<0x143, 0xC>(x);   // row_bcast:31 -> rows 2,3
    return __int_as_float(__builtin_amdgcn_readlane(__float_as_int(x), 63));
}

// ---------------------------------------------------------------------------
// Expert MLP: one block per node. h1 = relu(x@W1[t]+b1[t]); emb = h1@W2[t]+b2[t]
// ---------------------------------------------------------------------------
__global__ __launch_bounds__(256) void mlp_kernel(
    const float* __restrict__ x, const int* __restrict__ types,
    const float* __restrict__ W1, const float* __restrict__ b1,
    const float* __restrict__ W2, const float* __restrict__ b2,
    float* __restrict__ emb)
{
    __shared__ float xs[IN_DIM];
    __shared__ float h1[MLP_HID];
    const int n = blockIdx.x;
    const int ty = types[n];
    const int tid = threadIdx.x;

    if (tid < IN_DIM) xs[tid] = x[n * IN_DIM + tid];
    __syncthreads();

    if (tid < MLP_HID) {
        const float* w = W1 + (size_t)ty * IN_DIM * MLP_HID;
        float acc = b1[ty * MLP_HID + tid];
        #pragma unroll 8
        for (int k = 0; k < IN_DIM; k++)
            acc += xs[k] * w[k * MLP_HID + tid];
        h1[tid] = fmaxf(acc, 0.f);
    }
    __syncthreads();

    const float* w2 = W2 + (size_t)ty * MLP_HID * EMB;
    #pragma unroll
    for (int j = tid; j < EMB; j += 256) {
        float acc = b2[ty * EMB + j];
        #pragma unroll 8
        for (int k = 0; k < MLP_HID; k++)
            acc += h1[k] * w2[k * EMB + j];
        emb[(size_t)n * EMB + j] = acc;
    }
}

// ---------------------------------------------------------------------------
// C[M,N] = A[M,K] @ B[N,K]^T + bias[N]   (fp32, 64x64 tile, BK=16)
// ---------------------------------------------------------------------------
#define BM 64
#define BN 64
#define BK 16
__global__ __launch_bounds__(256) void gemm_bt_bias(
    const float* __restrict__ A, const float* __restrict__ B,
    const float* __restrict__ bias, float* __restrict__ C,
    int M, int N, int K)
{
    __shared__ float As[BK][BM + 1];
    __shared__ float Bs[BK][BN + 1];
    const int bm = blockIdx.y * BM, bn = blockIdx.x * BN;
    const int tid = threadIdx.x;
    const int tx = tid & 15, tyy = tid >> 4;   // 16x16 thread grid
    const int lr = tid >> 2;                   // loader row 0..63
    const int lk = (tid & 3) * 4;              // loader k offset

    float acc[4][4] = {};

    for (int k0 = 0; k0 < K; k0 += BK) {
        float4 av = *(const float4*)(A + (size_t)(bm + lr) * K + k0 + lk);
        float4 bv = *(const float4*)(B + (size_t)(bn + lr) * K + k0 + lk);
        As[lk + 0][lr] = av.x; As[lk + 1][lr] = av.y;
        As[lk + 2][lr] = av.z; As[lk + 3][lr] = av.w;
        Bs[lk + 0][lr] = bv.x; Bs[lk + 1][lr] = bv.y;
        Bs[lk + 2][lr] = bv.z; Bs[lk + 3][lr] = bv.w;
        __syncthreads();
        #pragma unroll
        for (int k = 0; k < BK; k++) {
            float a[4], b[4];
            #pragma unroll
            for (int i = 0; i < 4; i++) a[i] = As[k][tyy * 4 + i];
            #pragma unroll
            for (int j = 0; j < 4; j++) b[j] = Bs[k][tx * 4 + j];
            #pragma unroll
            for (int i = 0; i < 4; i++)
                #pragma unroll
                for (int j = 0; j < 4; j++)
                    acc[i][j] += a[i] * b[j];
        }
        __syncthreads();
    }

    #pragma unroll
    for (int i = 0; i < 4; i++) {
        const int row = bm + tyy * 4 + i;
        #pragma unroll
        for (int j = 0; j < 4; j++) {
            const int col = bn + tx * 4 + j;
            C[(size_t)row * N + col] = acc[i][j] + bias[col];
        }
    }
}

// ---------------------------------------------------------------------------
// Fused 2-layer GRU scan. 256 blocks (1/CU), 512 threads (8 waves, 2/SIMD).
// Waves 0-3 = L0 engine, waves 4-7 = L1 engine. R13 pipeline-offset: eng1
// runs D(e-1) with h0(e-2)=hr0_prev and h1(e-2) polled at tag e-2 (ready,
// round-1 hit); eng0 runs B(e) with fresh tag e-1 poll. R14 DPP joint
// reduce (wave_sum64, gate math wave-uniform).
//
// R15: 8-WAY REPLICATED EXCHANGE RINGS. R14's FETCH (937MB ~= 8192 steps
// x 16KB x 8 XCDs) shows the dispatch's EA traffic is ~all hbuf refetch:
// every step all 256 blocks re-request the SAME 128 lines per ring ->
// 256 requesters/line/round at the coherence point (hotspot; the old
// congestion outliers were its unstable mode). Now each publisher stores
// its tagged word to NREP=8 replicas (fire-and-forget, off-chain) and
// each block polls ONLY replica blockIdx&7. With round-robin block->XCD
// dispatch, replica k is read only by XCD k: 32 requesters/line, replica
// lines home in one XCD's L2, per-XCD fetch volume unchanged. Poll
// protocol/tags/barriers/schedule byte-identical to R14 (single variable).
//
// Anti-lap per replica (depth-2 ring): X posts tag e to ALL replicas only
// after X's S1(e) proved every tag e-1 present on X's replica; any reader
// Y of replica r posted its tag e-1 (to all replicas) only after Y's
// S1(e-1), i.e. after Y's tag e-2 reads on r retired — verbatim R9
// argument with "publish-to-all, read-one".
//
// Rings live in the emb region (dead after the GEMM reads it), poisoned
// 0xAA by an in-stream hipMemsetAsync between GEMM and this kernel
// (graph-capture-safe; tag 0xAAAAAAAA never matches an epoch <= T+2).
// ---------------------------------------------------------------------------
#define WLDS_FLOATS (36 * 1024)          // 147456 B
#define HL0_OFF WLDS_FLOATS
#define HL1_OFF (WLDS_FLOATS + HID)

__global__ __launch_bounds__(512, 1) void gru_fused(
    const float* __restrict__ gi0,   // [T, 3072] layer-0 input gates (incl. bih0)
    const float* __restrict__ Whh0, const float* __restrict__ bhh0,
    const float* __restrict__ Wih1, const float* __restrict__ bih1,
    const float* __restrict__ Whh1, const float* __restrict__ bhh1,
    const float* __restrict__ h_init,   // [2, 1024]
    u64* __restrict__ hbuf0,            // [NREP][2][1024] tagged rings, layer 0
    u64* __restrict__ hbuf1,            // [NREP][2][1024] tagged rings, layer 1
    float* __restrict__ hout,           // [1024] final h1
    int T)
{
    __shared__ float lds[WLDS_FLOATS + 2 * HID];   // 155648 B

    const int tid = threadIdx.x;
    const int b = blockIdx.x;
    const int eng = tid >> 8;          // 0: L0 engine, 1: L1 engine
    const int etid = tid & 255;        // engine-local thread id
    const int wv = (tid >> 6) & 3;     // engine-local wave 0..3
    const int lane = tid & 63;
    const int d = b * 4 + wv;          // owned dim (per engine)

    // replica this block reads (with %8 XCD round-robin: replica == XCD id)
    const u64* rd0 = hbuf0 + (size_t)(b & (NREP - 1)) * (2 * HID);
    const u64* rd1 = hbuf1 + (size_t)(b & (NREP - 1)) * (2 * HID);

    float* hl0 = &lds[HL0_OFF];
    float* hl1 = &lds[HL1_OFF];

    // ---- stage 36 weight rows into LDS (once); layout: lds[(dl*9+r)*HID] ----
    for (int i = tid; i < 36 * 256; i += 512) {
        const int p = i >> 8;          // row 0..35 (= dl*9 + r)
        const int elem = i & 255;      // float4 index within the 1024-row
        const int dl = p / 9, r = p % 9;
        const int m = r / 3, g = r % 3;
        const float* src = (m == 0 ? Whh0 : (m == 1 ? Wih1 : Whh1))
                           + (size_t)(g * HID + b * 4 + dl) * HID;
        ((float4*)&lds[p * HID])[elem] = ((const float4*)src)[elem];
    }
    __syncthreads();

    // per-engine constants / state (wave-uniform; no lane guards)
    float bh00 = 0.f, bh01 = 0.f, bh02 = 0.f;
    float bi10 = 0.f, bi11 = 0.f, bi12 = 0.f;
    float bh10 = 0.f, bh11 = 0.f, bh12 = 0.f;
    float hprev0 = 0.f, hprev1 = 0.f;
    float gc0 = 0.f, gc1 = 0.f, gc2 = 0.f;
    if (eng == 0) {
        bh00 = bhh0[d]; bh01 = bhh0[HID + d]; bh02 = bhh0[2 * HID + d];
        hprev0 = h_init[d];
        gc0 = gi0[d]; gc1 = gi0[HID + d]; gc2 = gi0[2 * HID + d];
    } else {
        bi10 = bih1[d]; bi11 = bih1[HID + d]; bi12 = bih1[2 * HID + d];
        bh10 = bhh1[d]; bh11 = bhh1[HID + d]; bh12 = bhh1[2 * HID + d];
        hprev1 = h_init[HID + d];
    }

    float4 hr0_prev[4] = {};   // eng1: h0 snapshot delayed one epoch

    for (int e = 1; e <= T + 2; e++) {
        // eng0: prefetch next epoch's gi0 row (same-address wave load ->
        // one broadcast transaction; in flight under the polls)
        float gn0 = 0.f, gn1 = 0.f, gn2 = 0.f;
        if (eng == 0 && e < T) {
            const float* g = gi0 + (size_t)e * G3;
            gn0 = g[d]; gn1 = g[HID + d]; gn2 = g[2 * HID + d];
        }

        // ===== concurrent POLL + FILL =====
        if (eng == 0) {
            if (e == 1) {
                #pragma unroll
                for (int j = 0; j < 4; j++)
                    hl0[etid + 256 * j] = h_init[etid + 256 * j];
            } else if (e <= T + 1) {
                const unsigned te = (unsigned)(e - 1);
                const u64* sa = rd0 + ((e - 1) & 1) * HID;
                u64 va[4];
                bool dn[4] = {false, false, false, false};
                for (;;) {
                    #pragma unroll
                    for (int j = 0; j < 4; j++)
                        if (!dn[j])
                            va[j] = __hip_atomic_load(&sa[etid + 256 * j], __ATOMIC_RELAXED,
                                                      __HIP_MEMORY_SCOPE_AGENT);
                    bool ok = true;
                    #pragma unroll
                    for (int j = 0; j < 4; j++) {
                        dn[j] = dn[j] || ((unsigned)(va[j] >> 32) == te);
                        ok &= dn[j];
                    }
                    if (ok) break;
                    __builtin_amdgcn_s_sleep(1);   // backoff: tame the poll storm
                }
                #pragma unroll
                for (int j = 0; j < 4; j++)
                    hl0[etid + 256 * j] = __uint_as_float((unsigned)va[j]);
            }
            // e == T+2: no fill (hl0 unread this epoch; eng1 uses hr0_prev)
        } else {
            if (e <= 3) {
                // h1-state for D(1)/D(2) bootstrap is h_init layer 1
                #pragma unroll
                for (int j = 0; j < 4; j++)
                    hl1[etid + 256 * j] = h_init[HID + etid + 256 * j];
            } else {
                // poll tag e-2: published a FULL epoch ago -> round-1 hit
                const unsigned te = (unsigned)(e - 2);
                const u64* sb = rd1 + ((e - 2) & 1) * HID;
                u64 vb[4];
                bool dn[4] = {false, false, false, false};
                for (;;) {
                    #pragma unroll
                    for (int j = 0; j < 4; j++)
                        if (!dn[j])
                            vb[j] = __hip_atomic_load(&sb[etid + 256 * j], __ATOMIC_RELAXED,
                                                      __HIP_MEMORY_SCOPE_AGENT);
                    bool ok = true;
                    #pragma unroll
                    for (int j = 0; j < 4; j++) {
                        dn[j] = dn[j] || ((unsigned)(vb[j] >> 32) == te);
                        ok &= dn[j];
                    }
                    if (ok) break;
                    __builtin_amdgcn_s_sleep(1);
                }
                #pragma unroll
                for (int j = 0; j < 4; j++)
                    hl1[etid + 256 * j] = __uint_as_float((unsigned)vb[j]);
            }
        }
        __syncthreads();   // S1: hl0 AND hl1 valid block-wide

        // ===== register snapshots (before S2 so next fill can't clobber) =====
        const float4* h0v4 = (const float4*)hl0;
        float4 hr0[4];
        #pragma unroll
        for (int j = 0; j < 4; j++) hr0[j] = h0v4[64 * j + lane];
        float4 hr1[4] = {};
        if (eng == 1) {
            const float4* h1v4 = (const float4*)hl1;
            #pragma unroll
            for (int j = 0; j < 4; j++) hr1[j] = h1v4[64 * j + lane];
        }
        __syncthreads();   // S2: all LDS reads retired; fills of e+1 are safe

        if (eng == 0) {
            // ===== L0 engine: B(e) — joint 3-gate accumulate + DPP reduce =====
            if (e <= T) {
                const float4* wr0 = (const float4*)&lds[(wv * 9 + 0) * HID];
                const float4* wr1 = (const float4*)&lds[(wv * 9 + 1) * HID];
                const float4* wr2 = (const float4*)&lds[(wv * 9 + 2) * HID];
                float4 a0 = {0.f, 0.f, 0.f, 0.f};
                float4 a1 = {0.f, 0.f, 0.f, 0.f};
                float4 a2 = {0.f, 0.f, 0.f, 0.f};
                #pragma unroll
                for (int j = 0; j < 4; j++) {
                    const float4 h = hr0[j];
                    const float4 w0 = wr0[64 * j + lane];
                    const float4 w1 = wr1[64 * j + lane];
                    const float4 w2 = wr2[64 * j + lane];
                    a0.x += w0.x * h.x; a0.y += w0.y * h.y; a0.z += w0.z * h.z; a0.w += w0.w * h.w;
                    a1.x += w1.x * h.x; a1.y += w1.y * h.y; a1.z += w1.z * h.z; a1.w += w1.w * h.w;
                    a2.x += w2.x * h.x; a2.y += w2.y * h.y; a2.z += w2.z * h.z; a2.w += w2.w * h.w;
                }
                const float s0 = wave_sum64((a0.x + a0.y) + (a0.z + a0.w));
                const float s1 = wave_sum64((a1.x + a1.y) + (a1.z + a1.w));
                const float s2 = wave_sum64((a2.x + a2.y) + (a2.z + a2.w));
                // gate math wave-uniform (s* uniform via readlane63)
                const float r = 1.f / (1.f + __expf(-(gc0 + s0 + bh00)));
                const float z = 1.f / (1.f + __expf(-(gc1 + s1 + bh01)));
                const float nn = tanhf(gc2 + r * (s2 + bh02));
                const float hnew = (1.f - z) * nn + z * hprev0;
                hprev0 = hnew;
                if (lane == 0) {
                    const u64 v = ((u64)(unsigned)e << 32) | (u64)__float_as_uint(hnew);
                    u64* dst = hbuf0 + (e & 1) * HID + d;
                    #pragma unroll
                    for (int r8 = 0; r8 < NREP; r8++)
                        __hip_atomic_store(dst + (size_t)r8 * (2 * HID), v,
                                           __ATOMIC_RELAXED, __HIP_MEMORY_SCOPE_AGENT);
                }
                gc0 = gn0; gc1 = gn1; gc2 = gn2;
            }
        } else {
            // ===== L1 engine: D(e-1) — joint 6-acc + DPP reduce (e >= 3) =====
            // consumes h0(e-2) = hr0_prev and h1(e-2) = hr1
            if (e >= 3) {
                const float4* wi0 = (const float4*)&lds[(wv * 9 + 3) * HID];
                const float4* wi1 = (const float4*)&lds[(wv * 9 + 4) * HID];
                const float4* wi2 = (const float4*)&lds[(wv * 9 + 5) * HID];
                const float4* wh0 = (const float4*)&lds[(wv * 9 + 6) * HID];
                const float4* wh1 = (const float4*)&lds[(wv * 9 + 7) * HID];
                const float4* wh2 = (const float4*)&lds[(wv * 9 + 8) * HID];
                float4 ai0 = {0.f,0.f,0.f,0.f}, ai1 = {0.f,0.f,0.f,0.f}, ai2 = {0.f,0.f,0.f,0.f};
                float4 ah0 = {0.f,0.f,0.f,0.f}, ah1 = {0.f,0.f,0.f,0.f}, ah2 = {0.f,0.f,0.f,0.f};
                #pragma unroll
                for (int j = 0; j < 4; j++) {
                    const float4 hp = hr0_prev[j];
                    const float4 h1v = hr1[j];
                    const float4 w0 = wi0[64 * j + lane];
                    const float4 w1 = wi1[64 * j + lane];
                    const float4 w2 = wi2[64 * j + lane];
                    const float4 v0 = wh0[64 * j + lane];
                    const float4 v1 = wh1[64 * j + lane];
                    const float4 v2 = wh2[64 * j + lane];
                    ai0.x += w0.x * hp.x; ai0.y += w0.y * hp.y; ai0.z += w0.z * hp.z; ai0.w += w0.w * hp.w;
                    ai1.x += w1.x * hp.x; ai1.y += w1.y * hp.y; ai1.z += w1.z * hp.z; ai1.w += w1.w * hp.w;
                    ai2.x += w2.x * hp.x; ai2.y += w2.y * hp.y; ai2.z += w2.z * hp.z; ai2.w += w2.w * hp.w;
                    ah0.x += v0.x * h1v.x; ah0.y += v0.y * h1v.y; ah0.z += v0.z * h1v.z; ah0.w += v0.w * h1v.w;
                    ah1.x += v1.x * h1v.x; ah1.y += v1.y * h1v.y; ah1.z += v1.z * h1v.z; ah1.w += v1.w * h1v.w;
                    ah2.x += v2.x * h1v.x; ah2.y += v2.y * h1v.y; ah2.z += v2.z * h1v.z; ah2.w += v2.w * h1v.w;
                }
                const float si0 = wave_sum64((ai0.x + ai0.y) + (ai0.z + ai0.w));
                const float si1 = wave_sum64((ai1.x + ai1.y) + (ai1.z + ai1.w));
                const float si2 = wave_sum64((ai2.x + ai2.y) + (ai2.z + ai2.w));
                const float sh0 = wave_sum64((ah0.x + ah0.y) + (ah0.z + ah0.w));
                const float sh1 = wave_sum64((ah1.x + ah1.y) + (ah1.z + ah1.w));
                const float sh2 = wave_sum64((ah2.x + ah2.y) + (ah2.z + ah2.w));
                const float r = 1.f / (1.f + __expf(-(si0 + bi10 + sh0 + bh10)));
                const float z = 1.f / (1.f + __expf(-(si1 + bi11 + sh1 + bh11)));
                const float nn = tanhf(si2 + bi12 + r * (sh2 + bh12));
                const float hnew = (1.f - z) * nn + z * hprev1;
                hprev1 = hnew;
                if (e <= T + 1) {
                    if (lane == 0) {
                        const u64 v = ((u64)(unsigned)(e - 1) << 32) | (u64)__float_as_uint(hnew);
                        u64* dst = hbuf1 + ((e - 1) & 1) * HID + d;
                        #pragma unroll
                        for (int r8 = 0; r8 < NREP; r8++)
                            __hip_atomic_store(dst + (size_t)r8 * (2 * HID), v,
                                               __ATOMIC_RELAXED, __HIP_MEMORY_SCOPE_AGENT);
                    }
                } else {
                    if (lane == 0) hout[d] = hnew;   // e == T+2: final h1 = out1[T]
                }
            }
            // delay h0 snapshot by one epoch for next D
            #pragma unroll
            for (int j = 0; j < 4; j++) hr0_prev[j] = hr0[j];
        }
    }
}

// ---------------------------------------------------------------------------
// out[o] = dot(fc_W[o,:], h) + fc_b[o]; 64 waves, 16 outputs each.
// ---------------------------------------------------------------------------
__global__ __launch_bounds__(256) void fc_kernel(
    const float* __restrict__ h, const float* __restrict__ W,
    const float* __restrict__ b, float* __restrict__ out)
{
    __shared__ float hs[HID];
    const int wv = blockIdx.x * 4 + (threadIdx.x >> 6);
    const int lane = threadIdx.x & 63;
    for (int i = threadIdx.x; i < HID; i += 256) hs[i] = h[i];
    __syncthreads();
    for (int o = wv * 16; o < wv * 16 + 16; o++) {
        float acc = 0.f;
        #pragma unroll
        for (int u = 0; u < 16; u++)
            acc += W[(size_t)o * HID + lane + 64 * u] * hs[lane + 64 * u];
        #pragma unroll
        for (int off = 32; off; off >>= 1)
            acc += __shfl_down(acc, off, 64);
        if (lane == 0) out[o] = acc + b[o];
    }
}

// ---------------------------------------------------------------------------
extern "C" void kernel_launch(void* const* d_in, const int* in_sizes, int n_in,
                              void* d_out, int out_size, void* d_ws, size_t ws_size,
                              hipStream_t stream)
{
    const float* node_feats = (const float*)d_in[0];
    const int*   node_types = (const int*)d_in[1];
    const float* W1   = (const float*)d_in[2];
    const float* b1   = (const float*)d_in[3];
    const float* W2   = (const float*)d_in[4];
    const float* b2   = (const float*)d_in[5];
    const float* Wih0 = (const float*)d_in[6];
    const float* Whh0 = (const float*)d_in[7];
    const float* bih0 = (const float*)d_in[8];
    const float* bhh0 = (const float*)d_in[9];
    const float* Wih1 = (const float*)d_in[10];
    const float* Whh1 = (const float*)d_in[11];
    const float* bih1 = (const float*)d_in[12];
    const float* bhh1 = (const float*)d_in[13];
    const float* h_init = (const float*)d_in[14];
    const float* fc_W = (const float*)d_in[15];
    const float* fc_b = (const float*)d_in[16];
    float* out = (float*)d_out;

    char* ws = (char*)d_ws;
    const size_t GI_OFF    = 0;                      // 8192*3072*4 = 100663296
    const size_t EMB_OFF   = 100663296;              // 8192*512*4  = 16777216
    const size_t HOUT_OFF  = 117440512;              // 1024*4      = 4096
    // Replicated exchange rings live at the HEAD of the emb region: emb is
    // dead after the GEMM reads it, and we re-poison these bytes with an
    // in-stream memset (graph-capture-safe) before the scan each launch.
    const size_t HBUF0_OFF = EMB_OFF;                          // NREP*2*1024*8 = 131072
    const size_t HBUF1_OFF = EMB_OFF + (size_t)NREP * 2 * HID * 8;   // +131072
    const size_t HBUF_BYTES = (size_t)NREP * 2 * HID * 8 * 2;  // 262144

    float* gi   = (float*)(ws + GI_OFF);
    float* emb  = (float*)(ws + EMB_OFF);
    float* hout = (float*)(ws + HOUT_OFF);
    u64* hbuf0  = (u64*)(ws + HBUF0_OFF);
    u64* hbuf1  = (u64*)(ws + HBUF1_OFF);

    // 1. Expert MLP -> emb [8192, 512]
    mlp_kernel<<<N_NODES, 256, 0, stream>>>(node_feats, node_types, W1, b1, W2, b2, emb);

    // 2. gi0 = emb @ Wih0^T + bih0  [8192, 3072]
    gemm_bt_bias<<<dim3(G3 / BN, N_NODES / BM), 256, 0, stream>>>(
        emb, Wih0, bih0, gi, N_NODES, G3, EMB);

    // 2b. poison the replicated rings (tag 0xAAAAAAAA matches no epoch).
    //     Stream-ordered after the GEMM's last read of emb.
    hipMemsetAsync(ws + HBUF0_OFF, 0xAA, HBUF_BYTES, stream);

    // 3. fused 2-layer scan (dual-engine offset, DPP reduce, 8-way rings)
    gru_fused<<<256, 512, 0, stream>>>(gi, Whh0, bhh0, Wih1, bih1, Whh1, bhh1,
                                       h_init, hbuf0, hbuf1, hout, SEQ);

    // 4. FC on final hidden state
    fc_kernel<<<16, 256, 0, stream>>>(hout, fc_W, fc_b, out);
}

// Round 8
// 17665.820 us; speedup vs baseline: 1.1009x; 1.1009x over previous
//
#include <hip/hip_runtime.h>
#include <hip/hip_bf16.h>
#include <math.h>

typedef unsigned long long u64;

// Sizes
#define N_NODES 8192
#define IN_DIM 64
#define MLP_HID 128
#define EMB 512
#define HID 1024
#define G3 (3*HID)   // 3072
#define SEQ 8192

// ---------------------------------------------------------------------------
// DPP wave64 sum: 6 VALU-latency stages. row_shr:1/2/4/8 -> per-16-row sums
// in lanes 15/31/47/63; row_bcast:15 (rows 1,3); row_bcast:31 (rows 2,3);
// readlane(63) -> wave-uniform. bound_ctrl=true: invalid src reads 0 (safe
// for +). All 64 lanes active in the compute region (guards wave-uniform).
// ---------------------------------------------------------------------------
template<int CTRL, int ROW_MASK>
__device__ __forceinline__ float dpp_add(float x) {
    int mv = __builtin_amdgcn_update_dpp(0, __float_as_int(x), CTRL, ROW_MASK, 0xF, true);
    return x + __int_as_float(mv);
}
__device__ __forceinline__ float wave_sum64(float x) {
    x = dpp_add<0x111, 0xF>(x);   // row_shr:1
    x = dpp_add<0x112, 0xF>(x);   // row_shr:2
    x = dpp_add<0x114, 0xF>(x);   // row_shr:4
    x = dpp_add<0x118, 0xF>(x);   // row_shr:8
    x = dpp_add<0x142, 0xA>(x);   // row_bcast:15 -> rows 1,3
    x = dpp_add<0x143, 0xC>(x);   // row_bcast:31 -> rows 2,3
    return __int_as_float(__builtin_amdgcn_readlane(__float_as_int(x), 63));
}

// ---------------------------------------------------------------------------
// Expert MLP: one block per node. h1 = relu(x@W1[t]+b1[t]); emb = h1@W2[t]+b2[t]
// ---------------------------------------------------------------------------
__global__ __launch_bounds__(256) void mlp_kernel(
    const float* __restrict__ x, const int* __restrict__ types,
    const float* __restrict__ W1, const float* __restrict__ b1,
    const float* __restrict__ W2, const float* __restrict__ b2,
    float* __restrict__ emb)
{
    __shared__ float xs[IN_DIM];
    __shared__ float h1[MLP_HID];
    const int n = blockIdx.x;
    const int ty = types[n];
    const int tid = threadIdx.x;

    if (tid < IN_DIM) xs[tid] = x[n * IN_DIM + tid];
    __syncthreads();

    if (tid < MLP_HID) {
        const float* w = W1 + (size_t)ty * IN_DIM * MLP_HID;
        float acc = b1[ty * MLP_HID + tid];
        #pragma unroll 8
        for (int k = 0; k < IN_DIM; k++)
            acc += xs[k] * w[k * MLP_HID + tid];
        h1[tid] = fmaxf(acc, 0.f);
    }
    __syncthreads();

    const float* w2 = W2 + (size_t)ty * MLP_HID * EMB;
    #pragma unroll
    for (int j = tid; j < EMB; j += 256) {
        float acc = b2[ty * EMB + j];
        #pragma unroll 8
        for (int k = 0; k < MLP_HID; k++)
            acc += h1[k] * w2[k * EMB + j];
        emb[(size_t)n * EMB + j] = acc;
    }
}

// ---------------------------------------------------------------------------
// C[M,N] = A[M,K] @ B[N,K]^T + bias[N]   (fp32, 64x64 tile, BK=16)
// ---------------------------------------------------------------------------
#define BM 64
#define BN 64
#define BK 16
__global__ __launch_bounds__(256) void gemm_bt_bias(
    const float* __restrict__ A, const float* __restrict__ B,
    const float* __restrict__ bias, float* __restrict__ C,
    int M, int N, int K)
{
    __shared__ float As[BK][BM + 1];
    __shared__ float Bs[BK][BN + 1];
    const int bm = blockIdx.y * BM, bn = blockIdx.x * BN;
    const int tid = threadIdx.x;
    const int tx = tid & 15, tyy = tid >> 4;   // 16x16 thread grid
    const int lr = tid >> 2;                   // loader row 0..63
    const int lk = (tid & 3) * 4;              // loader k offset

    float acc[4][4] = {};

    for (int k0 = 0; k0 < K; k0 += BK) {
        float4 av = *(const float4*)(A + (size_t)(bm + lr) * K + k0 + lk);
        float4 bv = *(const float4*)(B + (size_t)(bn + lr) * K + k0 + lk);
        As[lk + 0][lr] = av.x; As[lk + 1][lr] = av.y;
        As[lk + 2][lr] = av.z; As[lk + 3][lr] = av.w;
        Bs[lk + 0][lr] = bv.x; Bs[lk + 1][lr] = bv.y;
        Bs[lk + 2][lr] = bv.z; Bs[lk + 3][lr] = bv.w;
        __syncthreads();
        #pragma unroll
        for (int k = 0; k < BK; k++) {
            float a[4], b[4];
            #pragma unroll
            for (int i = 0; i < 4; i++) a[i] = As[k][tyy * 4 + i];
            #pragma unroll
            for (int j = 0; j < 4; j++) b[j] = Bs[k][tx * 4 + j];
            #pragma unroll
            for (int i = 0; i < 4; i++)
                #pragma unroll
                for (int j = 0; j < 4; j++)
                    acc[i][j] += a[i] * b[j];
        }
        __syncthreads();
    }

    #pragma unroll
    for (int i = 0; i < 4; i++) {
        const int row = bm + tyy * 4 + i;
        #pragma unroll
        for (int j = 0; j < 4; j++) {
            const int col = bn + tx * 4 + j;
            C[(size_t)row * N + col] = acc[i][j] + bias[col];
        }
    }
}

// ---------------------------------------------------------------------------
// Fused 2-layer GRU scan. 256 blocks (1/CU), 512 threads (8 waves, 2/SIMD).
// Waves 0-3 = L0 engine, waves 4-7 = L1 engine. R13 pipeline-offset: eng1
// runs D(e-1) with h0(e-2)=hr0_prev and h1(e-2) polled at tag e-2 (ready,
// round-1 hit); eng0 runs B(e) with fresh tag e-1 poll. R14 DPP joint
// reduce (wave_sum64, gate math wave-uniform).
//
// R15 POST-MORTEM: 8-way ring replication = flat (read path is NOT
// serialization-limited); reverted to the proven R14 single-ring protocol.
//
// R16 (resubmit — R7's bench was an infra failure, no kernel verdict):
// WEIGHTS IN REGISTERS. The weight rows are epoch-invariant, yet both
// engines re-read them from LDS every step (eng0: 12 ds_read_b128 ON the
// serial chain, ~150-250cy; eng1: 24 off-chain). Hoisted once into VGPRs
// before the loop: eng0 12 float4 (48 VGPR), eng1 24 float4 (96 VGPR),
// worst-path ~190 VGPR < 256 so 2 waves/SIMD still fit. All weight-array
// indices are compile-time constants (no scratch). LDS weight staging
// deleted — LDS is now just the two 4KB h-broadcast buffers. Poll
// protocol/tags/barriers/schedule byte-identical to R14.
//
// Anti-lap per buffer (depth-2 ring) unchanged — verbatim R9/R13 argument.
// hbufs start 0xAA-poisoned by the harness: tag 0xAAAAAAAA never matches
// an epoch in [1, T+2], so no memset needed.
// ---------------------------------------------------------------------------
__global__ __launch_bounds__(512, 1) void gru_fused(
    const float* __restrict__ gi0,   // [T, 3072] layer-0 input gates (incl. bih0)
    const float* __restrict__ Whh0, const float* __restrict__ bhh0,
    const float* __restrict__ Wih1, const float* __restrict__ bih1,
    const float* __restrict__ Whh1, const float* __restrict__ bhh1,
    const float* __restrict__ h_init,   // [2, 1024]
    u64* __restrict__ hbuf0,            // [2][1024] tagged ring, layer 0
    u64* __restrict__ hbuf1,            // [2][1024] tagged ring, layer 1
    float* __restrict__ hout,           // [1024] final h1
    int T)
{
    __shared__ float hl0[HID];          // layer-0 h broadcast buffer (4 KB)
    __shared__ float hl1[HID];          // layer-1 h broadcast buffer (4 KB)

    const int tid = threadIdx.x;
    const int b = blockIdx.x;
    const int eng = tid >> 8;          // 0: L0 engine, 1: L1 engine
    const int etid = tid & 255;        // engine-local thread id
    const int wv = (tid >> 6) & 3;     // engine-local wave 0..3
    const int lane = tid & 63;
    const int d = b * 4 + wv;          // owned dim (per engine)

    // ---- hoist weights into registers (epoch-invariant; indices static) ----
    // eng0: WA[g][j] = Whh0 row (g*HID+d), lane's float4 at 256j+4*lane
    // eng1: WA[g][j] = Wih1 row, WB[g][j] = Whh1 row
    float4 WA[3][4];
    float4 WB[3][4] = {};
    if (eng == 0) {
        #pragma unroll
        for (int g = 0; g < 3; g++)
            #pragma unroll
            for (int j = 0; j < 4; j++)
                WA[g][j] = *(const float4*)(Whh0 + (size_t)(g * HID + d) * HID + 256 * j + 4 * lane);
    } else {
        #pragma unroll
        for (int g = 0; g < 3; g++)
            #pragma unroll
            for (int j = 0; j < 4; j++) {
                WA[g][j] = *(const float4*)(Wih1 + (size_t)(g * HID + d) * HID + 256 * j + 4 * lane);
                WB[g][j] = *(const float4*)(Whh1 + (size_t)(g * HID + d) * HID + 256 * j + 4 * lane);
            }
    }

    // per-engine constants / state (wave-uniform; no lane guards)
    float bh00 = 0.f, bh01 = 0.f, bh02 = 0.f;
    float bi10 = 0.f, bi11 = 0.f, bi12 = 0.f;
    float bh10 = 0.f, bh11 = 0.f, bh12 = 0.f;
    float hprev0 = 0.f, hprev1 = 0.f;
    float gc0 = 0.f, gc1 = 0.f, gc2 = 0.f;
    if (eng == 0) {
        bh00 = bhh0[d]; bh01 = bhh0[HID + d]; bh02 = bhh0[2 * HID + d];
        hprev0 = h_init[d];
        gc0 = gi0[d]; gc1 = gi0[HID + d]; gc2 = gi0[2 * HID + d];
    } else {
        bi10 = bih1[d]; bi11 = bih1[HID + d]; bi12 = bih1[2 * HID + d];
        bh10 = bhh1[d]; bh11 = bhh1[HID + d]; bh12 = bhh1[2 * HID + d];
        hprev1 = h_init[HID + d];
    }

    float4 hr0_prev[4] = {};   // eng1: h0 snapshot delayed one epoch

    for (int e = 1; e <= T + 2; e++) {
        // eng0: prefetch next epoch's gi0 row (same-address wave load ->
        // one broadcast transaction; in flight under the polls)
        float gn0 = 0.f, gn1 = 0.f, gn2 = 0.f;
        if (eng == 0 && e < T) {
            const float* g = gi0 + (size_t)e * G3;
            gn0 = g[d]; gn1 = g[HID + d]; gn2 = g[2 * HID + d];
        }

        // ===== concurrent POLL + FILL =====
        if (eng == 0) {
            if (e == 1) {
                #pragma unroll
                for (int j = 0; j < 4; j++)
                    hl0[etid + 256 * j] = h_init[etid + 256 * j];
            } else if (e <= T + 1) {
                const unsigned te = (unsigned)(e - 1);
                const u64* sa = hbuf0 + ((e - 1) & 1) * HID;
                u64 va[4];
                bool dn[4] = {false, false, false, false};
                for (;;) {
                    #pragma unroll
                    for (int j = 0; j < 4; j++)
                        if (!dn[j])
                            va[j] = __hip_atomic_load(&sa[etid + 256 * j], __ATOMIC_RELAXED,
                                                      __HIP_MEMORY_SCOPE_AGENT);
                    bool ok = true;
                    #pragma unroll
                    for (int j = 0; j < 4; j++) {
                        dn[j] = dn[j] || ((unsigned)(va[j] >> 32) == te);
                        ok &= dn[j];
                    }
                    if (ok) break;
                    __builtin_amdgcn_s_sleep(1);   // backoff: tame the poll storm
                }
                #pragma unroll
                for (int j = 0; j < 4; j++)
                    hl0[etid + 256 * j] = __uint_as_float((unsigned)va[j]);
            }
            // e == T+2: no fill (hl0 unread this epoch; eng1 uses hr0_prev)
        } else {
            if (e <= 3) {
                // h1-state for D(1)/D(2) bootstrap is h_init layer 1
                #pragma unroll
                for (int j = 0; j < 4; j++)
                    hl1[etid + 256 * j] = h_init[HID + etid + 256 * j];
            } else {
                // poll tag e-2: published a FULL epoch ago -> round-1 hit
                const unsigned te = (unsigned)(e - 2);
                const u64* sb = hbuf1 + ((e - 2) & 1) * HID;
                u64 vb[4];
                bool dn[4] = {false, false, false, false};
                for (;;) {
                    #pragma unroll
                    for (int j = 0; j < 4; j++)
                        if (!dn[j])
                            vb[j] = __hip_atomic_load(&sb[etid + 256 * j], __ATOMIC_RELAXED,
                                                      __HIP_MEMORY_SCOPE_AGENT);
                    bool ok = true;
                    #pragma unroll
                    for (int j = 0; j < 4; j++) {
                        dn[j] = dn[j] || ((unsigned)(vb[j] >> 32) == te);
                        ok &= dn[j];
                    }
                    if (ok) break;
                    __builtin_amdgcn_s_sleep(1);
                }
                #pragma unroll
                for (int j = 0; j < 4; j++)
                    hl1[etid + 256 * j] = __uint_as_float((unsigned)vb[j]);
            }
        }
        __syncthreads();   // S1: hl0 AND hl1 valid block-wide

        // ===== register snapshots (before S2 so next fill can't clobber) =====
        const float4* h0v4 = (const float4*)hl0;
        float4 hr0[4];
        #pragma unroll
        for (int j = 0; j < 4; j++) hr0[j] = h0v4[64 * j + lane];
        float4 hr1[4] = {};
        if (eng == 1) {
            const float4* h1v4 = (const float4*)hl1;
            #pragma unroll
            for (int j = 0; j < 4; j++) hr1[j] = h1v4[64 * j + lane];
        }
        __syncthreads();   // S2: all LDS reads retired; fills of e+1 are safe

        if (eng == 0) {
            // ===== L0 engine: B(e) — joint 3-gate accumulate + DPP reduce =====
            if (e <= T) {
                float4 a0 = {0.f, 0.f, 0.f, 0.f};
                float4 a1 = {0.f, 0.f, 0.f, 0.f};
                float4 a2 = {0.f, 0.f, 0.f, 0.f};
                #pragma unroll
                for (int j = 0; j < 4; j++) {
                    const float4 h = hr0[j];
                    a0.x += WA[0][j].x * h.x; a0.y += WA[0][j].y * h.y;
                    a0.z += WA[0][j].z * h.z; a0.w += WA[0][j].w * h.w;
                    a1.x += WA[1][j].x * h.x; a1.y += WA[1][j].y * h.y;
                    a1.z += WA[1][j].z * h.z; a1.w += WA[1][j].w * h.w;
                    a2.x += WA[2][j].x * h.x; a2.y += WA[2][j].y * h.y;
                    a2.z += WA[2][j].z * h.z; a2.w += WA[2][j].w * h.w;
                }
                const float s0 = wave_sum64((a0.x + a0.y) + (a0.z + a0.w));
                const float s1 = wave_sum64((a1.x + a1.y) + (a1.z + a1.w));
                const float s2 = wave_sum64((a2.x + a2.y) + (a2.z + a2.w));
                // gate math wave-uniform (s* uniform via readlane63)
                const float r = 1.f / (1.f + __expf(-(gc0 + s0 + bh00)));
                const float z = 1.f / (1.f + __expf(-(gc1 + s1 + bh01)));
                const float nn = tanhf(gc2 + r * (s2 + bh02));
                const float hnew = (1.f - z) * nn + z * hprev0;
                hprev0 = hnew;
                if (lane == 0) {
                    const u64 v = ((u64)(unsigned)e << 32) | (u64)__float_as_uint(hnew);
                    __hip_atomic_store(&hbuf0[(e & 1) * HID + d], v,
                                       __ATOMIC_RELAXED, __HIP_MEMORY_SCOPE_AGENT);
                }
                gc0 = gn0; gc1 = gn1; gc2 = gn2;
            }
        } else {
            // ===== L1 engine: D(e-1) — joint 6-acc + DPP reduce (e >= 3) =====
            // consumes h0(e-2) = hr0_prev and h1(e-2) = hr1
            if (e >= 3) {
                float4 ai0 = {0.f,0.f,0.f,0.f}, ai1 = {0.f,0.f,0.f,0.f}, ai2 = {0.f,0.f,0.f,0.f};
                float4 ah0 = {0.f,0.f,0.f,0.f}, ah1 = {0.f,0.f,0.f,0.f}, ah2 = {0.f,0.f,0.f,0.f};
                #pragma unroll
                for (int j = 0; j < 4; j++) {
                    const float4 hp = hr0_prev[j];
                    const float4 h1v = hr1[j];
                    ai0.x += WA[0][j].x * hp.x; ai0.y += WA[0][j].y * hp.y;
                    ai0.z += WA[0][j].z * hp.z; ai0.w += WA[0][j].w * hp.w;
                    ai1.x += WA[1][j].x * hp.x; ai1.y += WA[1][j].y * hp.y;
                    ai1.z += WA[1][j].z * hp.z; ai1.w += WA[1][j].w * hp.w;
                    ai2.x += WA[2][j].x * hp.x; ai2.y += WA[2][j].y * hp.y;
                    ai2.z += WA[2][j].z * hp.z; ai2.w += WA[2][j].w * hp.w;
                    ah0.x += WB[0][j].x * h1v.x; ah0.y += WB[0][j].y * h1v.y;
                    ah0.z += WB[0][j].z * h1v.z; ah0.w += WB[0][j].w * h1v.w;
                    ah1.x += WB[1][j].x * h1v.x; ah1.y += WB[1][j].y * h1v.y;
                    ah1.z += WB[1][j].z * h1v.z; ah1.w += WB[1][j].w * h1v.w;
                    ah2.x += WB[2][j].x * h1v.x; ah2.y += WB[2][j].y * h1v.y;
                    ah2.z += WB[2][j].z * h1v.z; ah2.w += WB[2][j].w * h1v.w;
                }
                const float si0 = wave_sum64((ai0.x + ai0.y) + (ai0.z + ai0.w));
                const float si1 = wave_sum64((ai1.x + ai1.y) + (ai1.z + ai1.w));
                const float si2 = wave_sum64((ai2.x + ai2.y) + (ai2.z + ai2.w));
                const float sh0 = wave_sum64((ah0.x + ah0.y) + (ah0.z + ah0.w));
                const float sh1 = wave_sum64((ah1.x + ah1.y) + (ah1.z + ah1.w));
                const float sh2 = wave_sum64((ah2.x + ah2.y) + (ah2.z + ah2.w));
                const float r = 1.f / (1.f + __expf(-(si0 + bi10 + sh0 + bh10)));
                const float z = 1.f / (1.f + __expf(-(si1 + bi11 + sh1 + bh11)));
                const float nn = tanhf(si2 + bi12 + r * (sh2 + bh12));
                const float hnew = (1.f - z) * nn + z * hprev1;
                hprev1 = hnew;
                if (e <= T + 1) {
                    if (lane == 0) {
                        const u64 v = ((u64)(unsigned)(e - 1) << 32) | (u64)__float_as_uint(hnew);
                        __hip_atomic_store(&hbuf1[((e - 1) & 1) * HID + d], v,
                                           __ATOMIC_RELAXED, __HIP_MEMORY_SCOPE_AGENT);
                    }
                } else {
                    if (lane == 0) hout[d] = hnew;   // e == T+2: final h1 = out1[T]
                }
            }
            // delay h0 snapshot by one epoch for next D
            #pragma unroll
            for (int j = 0; j < 4; j++) hr0_prev[j] = hr0[j];
        }
    }
}

// ---------------------------------------------------------------------------
// out[o] = dot(fc_W[o,:], h) + fc_b[o]; 64 waves, 16 outputs each.
// ---------------------------------------------------------------------------
__global__ __launch_bounds__(256) void fc_kernel(
    const float* __restrict__ h, const float* __restrict__ W,
    const float* __restrict__ b, float* __restrict__ out)
{
    __shared__ float hs[HID];
    const int wv = blockIdx.x * 4 + (threadIdx.x >> 6);
    const int lane = threadIdx.x & 63;
    for (int i = threadIdx.x; i < HID; i += 256) hs[i] = h[i];
    __syncthreads();
    for (int o = wv * 16; o < wv * 16 + 16; o++) {
        float acc = 0.f;
        #pragma unroll
        for (int u = 0; u < 16; u++)
            acc += W[(size_t)o * HID + lane + 64 * u] * hs[lane + 64 * u];
        #pragma unroll
        for (int off = 32; off; off >>= 1)
            acc += __shfl_down(acc, off, 64);
        if (lane == 0) out[o] = acc + b[o];
    }
}

// ---------------------------------------------------------------------------
extern "C" void kernel_launch(void* const* d_in, const int* in_sizes, int n_in,
                              void* d_out, int out_size, void* d_ws, size_t ws_size,
                              hipStream_t stream)
{
    const float* node_feats = (const float*)d_in[0];
    const int*   node_types = (const int*)d_in[1];
    const float* W1   = (const float*)d_in[2];
    const float* b1   = (const float*)d_in[3];
    const float* W2   = (const float*)d_in[4];
    const float* b2   = (const float*)d_in[5];
    const float* Wih0 = (const float*)d_in[6];
    const float* Whh0 = (const float*)d_in[7];
    const float* bih0 = (const float*)d_in[8];
    const float* bhh0 = (const float*)d_in[9];
    const float* Wih1 = (const float*)d_in[10];
    const float* Whh1 = (const float*)d_in[11];
    const float* bih1 = (const float*)d_in[12];
    const float* bhh1 = (const float*)d_in[13];
    const float* h_init = (const float*)d_in[14];
    const float* fc_W = (const float*)d_in[15];
    const float* fc_b = (const float*)d_in[16];
    float* out = (float*)d_out;

    char* ws = (char*)d_ws;
    const size_t GI_OFF    = 0;                      // 8192*3072*4 = 100663296
    const size_t EMB_OFF   = 100663296;              // 8192*512*4  = 16777216
    const size_t HOUT_OFF  = 117440512;              // 1024*4      = 4096
    const size_t HBUF0_OFF = 117444608;              // 2048*8      = 16384
    const size_t HBUF1_OFF = 117460992;              // 2048*8      = 16384

    float* gi   = (float*)(ws + GI_OFF);
    float* emb  = (float*)(ws + EMB_OFF);
    float* hout = (float*)(ws + HOUT_OFF);
    u64* hbuf0  = (u64*)(ws + HBUF0_OFF);
    u64* hbuf1  = (u64*)(ws + HBUF1_OFF);
    // hbufs start 0xAA-poisoned: tag 0xAAAAAAAA never matches an epoch in
    // [1, 8194], so no memset needed anywhere.

    // 1. Expert MLP -> emb [8192, 512]
    mlp_kernel<<<N_NODES, 256, 0, stream>>>(node_feats, node_types, W1, b1, W2, b2, emb);

    // 2. gi0 = emb @ Wih0^T + bih0  [8192, 3072]
    gemm_bt_bias<<<dim3(G3 / BN, N_NODES / BM), 256, 0, stream>>>(
        emb, Wih0, bih0, gi, N_NODES, G3, EMB);

    // 3. fused 2-layer scan (dual-engine offset, DPP reduce, weights in VGPR)
    gru_fused<<<256, 512, 0, stream>>>(gi, Whh0, bhh0, Wih1, bih1, Whh1, bhh1,
                                       h_init, hbuf0, hbuf1, hout, SEQ);

    // 4. FC on final hidden state
    fc_kernel<<<16, 256, 0, stream>>>(hout, fc_W, fc_b, out);
}

// Round 9
// 16698.151 us; speedup vs baseline: 1.1647x; 1.0580x over previous
//
#include <hip/hip_runtime.h>
#include <hip/hip_bf16.h>
#include <math.h>

typedef unsigned long long u64;

// Sizes
#define N_NODES 8192
#define IN_DIM 64
#define MLP_HID 128
#define EMB 512
#define HID 1024
#define G3 (3*HID)   // 3072
#define SEQ 8192

// ---------------------------------------------------------------------------
// DPP wave64 sum: 6 VALU-latency stages. row_shr:1/2/4/8 -> per-16-row sums
// in lanes 15/31/47/63; row_bcast:15 (rows 1,3); row_bcast:31 (rows 2,3);
// readlane(63) -> wave-uniform. bound_ctrl=true: invalid src reads 0 (safe
// for +). All 64 lanes active in the compute region (guards wave-uniform).
// ---------------------------------------------------------------------------
template<int CTRL, int ROW_MASK>
__device__ __forceinline__ float dpp_add(float x) {
    int mv = __builtin_amdgcn_update_dpp(0, __float_as_int(x), CTRL, ROW_MASK, 0xF, true);
    return x + __int_as_float(mv);
}
__device__ __forceinline__ float wave_sum64(float x) {
    x = dpp_add<0x111, 0xF>(x);   // row_shr:1
    x = dpp_add<0x112, 0xF>(x);   // row_shr:2
    x = dpp_add<0x114, 0xF>(x);   // row_shr:4
    x = dpp_add<0x118, 0xF>(x);   // row_shr:8
    x = dpp_add<0x142, 0xA>(x);   // row_bcast:15 -> rows 1,3
    x = dpp_add<0x143, 0xC>(x);   // row_bcast:31 -> rows 2,3
    return __int_as_float(__builtin_amdgcn_readlane(__float_as_int(x), 63));
}

// ---------------------------------------------------------------------------
// Expert MLP: one block per node. h1 = relu(x@W1[t]+b1[t]); emb = h1@W2[t]+b2[t]
// ---------------------------------------------------------------------------
__global__ __launch_bounds__(256) void mlp_kernel(
    const float* __restrict__ x, const int* __restrict__ types,
    const float* __restrict__ W1, const float* __restrict__ b1,
    const float* __restrict__ W2, const float* __restrict__ b2,
    float* __restrict__ emb)
{
    __shared__ float xs[IN_DIM];
    __shared__ float h1[MLP_HID];
    const int n = blockIdx.x;
    const int ty = types[n];
    const int tid = threadIdx.x;

    if (tid < IN_DIM) xs[tid] = x[n * IN_DIM + tid];
    __syncthreads();

    if (tid < MLP_HID) {
        const float* w = W1 + (size_t)ty * IN_DIM * MLP_HID;
        float acc = b1[ty * MLP_HID + tid];
        #pragma unroll 8
        for (int k = 0; k < IN_DIM; k++)
            acc += xs[k] * w[k * MLP_HID + tid];
        h1[tid] = fmaxf(acc, 0.f);
    }
    __syncthreads();

    const float* w2 = W2 + (size_t)ty * MLP_HID * EMB;
    #pragma unroll
    for (int j = tid; j < EMB; j += 256) {
        float acc = b2[ty * EMB + j];
        #pragma unroll 8
        for (int k = 0; k < MLP_HID; k++)
            acc += h1[k] * w2[k * EMB + j];
        emb[(size_t)n * EMB + j] = acc;
    }
}

// ---------------------------------------------------------------------------
// C[M,N] = A[M,K] @ B[N,K]^T + bias[N]   (fp32, 64x64 tile, BK=16)
// ---------------------------------------------------------------------------
#define BM 64
#define BN 64
#define BK 16
__global__ __launch_bounds__(256) void gemm_bt_bias(
    const float* __restrict__ A, const float* __restrict__ B,
    const float* __restrict__ bias, float* __restrict__ C,
    int M, int N, int K)
{
    __shared__ float As[BK][BM + 1];
    __shared__ float Bs[BK][BN + 1];
    const int bm = blockIdx.y * BM, bn = blockIdx.x * BN;
    const int tid = threadIdx.x;
    const int tx = tid & 15, tyy = tid >> 4;   // 16x16 thread grid
    const int lr = tid >> 2;                   // loader row 0..63
    const int lk = (tid & 3) * 4;              // loader k offset

    float acc[4][4] = {};

    for (int k0 = 0; k0 < K; k0 += BK) {
        float4 av = *(const float4*)(A + (size_t)(bm + lr) * K + k0 + lk);
        float4 bv = *(const float4*)(B + (size_t)(bn + lr) * K + k0 + lk);
        As[lk + 0][lr] = av.x; As[lk + 1][lr] = av.y;
        As[lk + 2][lr] = av.z; As[lk + 3][lr] = av.w;
        Bs[lk + 0][lr] = bv.x; Bs[lk + 1][lr] = bv.y;
        Bs[lk + 2][lr] = bv.z; Bs[lk + 3][lr] = bv.w;
        __syncthreads();
        #pragma unroll
        for (int k = 0; k < BK; k++) {
            float a[4], b[4];
            #pragma unroll
            for (int i = 0; i < 4; i++) a[i] = As[k][tyy * 4 + i];
            #pragma unroll
            for (int j = 0; j < 4; j++) b[j] = Bs[k][tx * 4 + j];
            #pragma unroll
            for (int i = 0; i < 4; i++)
                #pragma unroll
                for (int j = 0; j < 4; j++)
                    acc[i][j] += a[i] * b[j];
        }
        __syncthreads();
    }

    #pragma unroll
    for (int i = 0; i < 4; i++) {
        const int row = bm + tyy * 4 + i;
        #pragma unroll
        for (int j = 0; j < 4; j++) {
            const int col = bn + tx * 4 + j;
            C[(size_t)row * N + col] = acc[i][j] + bias[col];
        }
    }
}

// ---------------------------------------------------------------------------
// Fused 2-layer GRU scan. 256 blocks (1/CU), 512 threads (8 waves, 2/SIMD).
// Waves 0-3 = L0 engine, waves 4-7 = L1 engine. R13 pipeline-offset: eng1
// runs D(e-1) with h0(e-2)=hr0_prev and h1(e-2) polled at tag e-2 (ready,
// round-1 hit); eng0 runs B(e) with fresh tag e-1 poll. R14 DPP joint
// reduce. R16 weights in VGPRs (12/24 float4, static indices).
//
// R17a: S2 REMOVED via double-buffered LDS h-buffers hl0[2]/hl1[2] (fill
// slot e&1, read slot e&1). Reuse safety: slot e&1 is next overwritten at
// epoch e+2, which begins only after S1(e+1); every consumer's snapshot(e)
// precedes its own arrival at S1(e+1) -> ordered by the barrier. eng1's
// hl1 is written and read by eng1 only (program order). The global-ring
// anti-lap proof never depended on S2 (publishes gate on S1) — verbatim.
//
// R17b: PRE-POLL DELAY s_sleep(2) (~128cy) on eng0's FRESH poll only.
// At poll start the peer publishes are ~0-300cy old but need ~400-500cy
// to become coherence-visible: round 1 was a near-guaranteed miss costing
// a full ~650cy RTT before round 2 hit. The delay shifts round 1 past the
// visibility horizon. It is a DELAY, not an added load (R10 ledger: loads
// may move, never duplicate) — coherent-load count per step unchanged.
// eng1's tag e-2 poll stays undelayed (already round-1 hit).
//
// Outlier diagnosis (R16 counters): the 47-58ms dispatches have IDENTICAL
// VALUBusy% with uniformly scaled duration/BW -> clock throttle (DVFS),
// not sync pathology. Environmental; not chased.
//
// hbufs start 0xAA-poisoned by the harness: tag 0xAAAAAAAA never matches
// an epoch in [1, T+2], so no memset needed.
// ---------------------------------------------------------------------------
__global__ __launch_bounds__(512, 1) void gru_fused(
    const float* __restrict__ gi0,   // [T, 3072] layer-0 input gates (incl. bih0)
    const float* __restrict__ Whh0, const float* __restrict__ bhh0,
    const float* __restrict__ Wih1, const float* __restrict__ bih1,
    const float* __restrict__ Whh1, const float* __restrict__ bhh1,
    const float* __restrict__ h_init,   // [2, 1024]
    u64* __restrict__ hbuf0,            // [2][1024] tagged ring, layer 0
    u64* __restrict__ hbuf1,            // [2][1024] tagged ring, layer 1
    float* __restrict__ hout,           // [1024] final h1
    int T)
{
    __shared__ float hl0[2][HID];       // layer-0 h broadcast, double-buffered
    __shared__ float hl1[2][HID];       // layer-1 h broadcast, double-buffered

    const int tid = threadIdx.x;
    const int b = blockIdx.x;
    const int eng = tid >> 8;          // 0: L0 engine, 1: L1 engine
    const int etid = tid & 255;        // engine-local thread id
    const int wv = (tid >> 6) & 3;     // engine-local wave 0..3
    const int lane = tid & 63;
    const int d = b * 4 + wv;          // owned dim (per engine)

    // ---- hoist weights into registers (epoch-invariant; indices static) ----
    // eng0: WA[g][j] = Whh0 row (g*HID+d), lane's float4 at 256j+4*lane
    // eng1: WA[g][j] = Wih1 row, WB[g][j] = Whh1 row
    float4 WA[3][4];
    float4 WB[3][4] = {};
    if (eng == 0) {
        #pragma unroll
        for (int g = 0; g < 3; g++)
            #pragma unroll
            for (int j = 0; j < 4; j++)
                WA[g][j] = *(const float4*)(Whh0 + (size_t)(g * HID + d) * HID + 256 * j + 4 * lane);
    } else {
        #pragma unroll
        for (int g = 0; g < 3; g++)
            #pragma unroll
            for (int j = 0; j < 4; j++) {
                WA[g][j] = *(const float4*)(Wih1 + (size_t)(g * HID + d) * HID + 256 * j + 4 * lane);
                WB[g][j] = *(const float4*)(Whh1 + (size_t)(g * HID + d) * HID + 256 * j + 4 * lane);
            }
    }

    // per-engine constants / state (wave-uniform; no lane guards)
    float bh00 = 0.f, bh01 = 0.f, bh02 = 0.f;
    float bi10 = 0.f, bi11 = 0.f, bi12 = 0.f;
    float bh10 = 0.f, bh11 = 0.f, bh12 = 0.f;
    float hprev0 = 0.f, hprev1 = 0.f;
    float gc0 = 0.f, gc1 = 0.f, gc2 = 0.f;
    if (eng == 0) {
        bh00 = bhh0[d]; bh01 = bhh0[HID + d]; bh02 = bhh0[2 * HID + d];
        hprev0 = h_init[d];
        gc0 = gi0[d]; gc1 = gi0[HID + d]; gc2 = gi0[2 * HID + d];
    } else {
        bi10 = bih1[d]; bi11 = bih1[HID + d]; bi12 = bih1[2 * HID + d];
        bh10 = bhh1[d]; bh11 = bhh1[HID + d]; bh12 = bhh1[2 * HID + d];
        hprev1 = h_init[HID + d];
    }

    float4 hr0_prev[4] = {};   // eng1: h0 snapshot delayed one epoch

    for (int e = 1; e <= T + 2; e++) {
        const int sl = e & 1;          // LDS double-buffer slot this epoch

        // eng0: prefetch next epoch's gi0 row (same-address wave load ->
        // one broadcast transaction; in flight under the polls)
        float gn0 = 0.f, gn1 = 0.f, gn2 = 0.f;
        if (eng == 0 && e < T) {
            const float* g = gi0 + (size_t)e * G3;
            gn0 = g[d]; gn1 = g[HID + d]; gn2 = g[2 * HID + d];
        }

        // ===== concurrent POLL + FILL =====
        if (eng == 0) {
            if (e == 1) {
                #pragma unroll
                for (int j = 0; j < 4; j++)
                    hl0[sl][etid + 256 * j] = h_init[etid + 256 * j];
            } else if (e <= T + 1) {
                // R17b: let the peers' fresh publishes become visible before
                // burning a poll round (~128cy < 1 wasted ~650cy RTT).
                __builtin_amdgcn_s_sleep(2);
                const unsigned te = (unsigned)(e - 1);
                const u64* sa = hbuf0 + ((e - 1) & 1) * HID;
                u64 va[4];
                bool dn[4] = {false, false, false, false};
                for (;;) {
                    #pragma unroll
                    for (int j = 0; j < 4; j++)
                        if (!dn[j])
                            va[j] = __hip_atomic_load(&sa[etid + 256 * j], __ATOMIC_RELAXED,
                                                      __HIP_MEMORY_SCOPE_AGENT);
                    bool ok = true;
                    #pragma unroll
                    for (int j = 0; j < 4; j++) {
                        dn[j] = dn[j] || ((unsigned)(va[j] >> 32) == te);
                        ok &= dn[j];
                    }
                    if (ok) break;
                    __builtin_amdgcn_s_sleep(1);   // backoff: tame the poll storm
                }
                #pragma unroll
                for (int j = 0; j < 4; j++)
                    hl0[sl][etid + 256 * j] = __uint_as_float((unsigned)va[j]);
            }
            // e == T+2: no fill (hl0 unread this epoch; eng1 uses hr0_prev)
        } else {
            if (e <= 3) {
                // h1-state for D(1)/D(2) bootstrap is h_init layer 1
                #pragma unroll
                for (int j = 0; j < 4; j++)
                    hl1[sl][etid + 256 * j] = h_init[HID + etid + 256 * j];
            } else {
                // poll tag e-2: published a FULL epoch ago -> round-1 hit
                const unsigned te = (unsigned)(e - 2);
                const u64* sb = hbuf1 + ((e - 2) & 1) * HID;
                u64 vb[4];
                bool dn[4] = {false, false, false, false};
                for (;;) {
                    #pragma unroll
                    for (int j = 0; j < 4; j++)
                        if (!dn[j])
                            vb[j] = __hip_atomic_load(&sb[etid + 256 * j], __ATOMIC_RELAXED,
                                                      __HIP_MEMORY_SCOPE_AGENT);
                    bool ok = true;
                    #pragma unroll
                    for (int j = 0; j < 4; j++) {
                        dn[j] = dn[j] || ((unsigned)(vb[j] >> 32) == te);
                        ok &= dn[j];
                    }
                    if (ok) break;
                    __builtin_amdgcn_s_sleep(1);
                }
                #pragma unroll
                for (int j = 0; j < 4; j++)
                    hl1[sl][etid + 256 * j] = __uint_as_float((unsigned)vb[j]);
            }
        }
        __syncthreads();   // S1: hl0[sl] AND hl1[sl] valid block-wide

        // ===== register snapshots (slot sl is next overwritten at e+2,
        //       which begins only after S1(e+1) — barrier-ordered) =====
        const float4* h0v4 = (const float4*)hl0[sl];
        float4 hr0[4];
        #pragma unroll
        for (int j = 0; j < 4; j++) hr0[j] = h0v4[64 * j + lane];
        float4 hr1[4] = {};
        if (eng == 1) {
            const float4* h1v4 = (const float4*)hl1[sl];
            #pragma unroll
            for (int j = 0; j < 4; j++) hr1[j] = h1v4[64 * j + lane];
        }
        // (no S2 — R17a)

        if (eng == 0) {
            // ===== L0 engine: B(e) — joint 3-gate accumulate + DPP reduce =====
            if (e <= T) {
                float4 a0 = {0.f, 0.f, 0.f, 0.f};
                float4 a1 = {0.f, 0.f, 0.f, 0.f};
                float4 a2 = {0.f, 0.f, 0.f, 0.f};
                #pragma unroll
                for (int j = 0; j < 4; j++) {
                    const float4 h = hr0[j];
                    a0.x += WA[0][j].x * h.x; a0.y += WA[0][j].y * h.y;
                    a0.z += WA[0][j].z * h.z; a0.w += WA[0][j].w * h.w;
                    a1.x += WA[1][j].x * h.x; a1.y += WA[1][j].y * h.y;
                    a1.z += WA[1][j].z * h.z; a1.w += WA[1][j].w * h.w;
                    a2.x += WA[2][j].x * h.x; a2.y += WA[2][j].y * h.y;
                    a2.z += WA[2][j].z * h.z; a2.w += WA[2][j].w * h.w;
                }
                const float s0 = wave_sum64((a0.x + a0.y) + (a0.z + a0.w));
                const float s1 = wave_sum64((a1.x + a1.y) + (a1.z + a1.w));
                const float s2 = wave_sum64((a2.x + a2.y) + (a2.z + a2.w));
                // gate math wave-uniform (s* uniform via readlane63)
                const float r = 1.f / (1.f + __expf(-(gc0 + s0 + bh00)));
                const float z = 1.f / (1.f + __expf(-(gc1 + s1 + bh01)));
                const float nn = tanhf(gc2 + r * (s2 + bh02));
                const float hnew = (1.f - z) * nn + z * hprev0;
                hprev0 = hnew;
                if (lane == 0) {
                    const u64 v = ((u64)(unsigned)e << 32) | (u64)__float_as_uint(hnew);
                    __hip_atomic_store(&hbuf0[(e & 1) * HID + d], v,
                                       __ATOMIC_RELAXED, __HIP_MEMORY_SCOPE_AGENT);
                }
                gc0 = gn0; gc1 = gn1; gc2 = gn2;
            }
        } else {
            // ===== L1 engine: D(e-1) — joint 6-acc + DPP reduce (e >= 3) =====
            // consumes h0(e-2) = hr0_prev and h1(e-2) = hr1
            if (e >= 3) {
                float4 ai0 = {0.f,0.f,0.f,0.f}, ai1 = {0.f,0.f,0.f,0.f}, ai2 = {0.f,0.f,0.f,0.f};
                float4 ah0 = {0.f,0.f,0.f,0.f}, ah1 = {0.f,0.f,0.f,0.f}, ah2 = {0.f,0.f,0.f,0.f};
                #pragma unroll
                for (int j = 0; j < 4; j++) {
                    const float4 hp = hr0_prev[j];
                    const float4 h1v = hr1[j];
                    ai0.x += WA[0][j].x * hp.x; ai0.y += WA[0][j].y * hp.y;
                    ai0.z += WA[0][j].z * hp.z; ai0.w += WA[0][j].w * hp.w;
                    ai1.x += WA[1][j].x * hp.x; ai1.y += WA[1][j].y * hp.y;
                    ai1.z += WA[1][j].z * hp.z; ai1.w += WA[1][j].w * hp.w;
                    ai2.x += WA[2][j].x * hp.x; ai2.y += WA[2][j].y * hp.y;
                    ai2.z += WA[2][j].z * hp.z; ai2.w += WA[2][j].w * hp.w;
                    ah0.x += WB[0][j].x * h1v.x; ah0.y += WB[0][j].y * h1v.y;
                    ah0.z += WB[0][j].z * h1v.z; ah0.w += WB[0][j].w * h1v.w;
                    ah1.x += WB[1][j].x * h1v.x; ah1.y += WB[1][j].y * h1v.y;
                    ah1.z += WB[1][j].z * h1v.z; ah1.w += WB[1][j].w * h1v.w;
                    ah2.x += WB[2][j].x * h1v.x; ah2.y += WB[2][j].y * h1v.y;
                    ah2.z += WB[2][j].z * h1v.z; ah2.w += WB[2][j].w * h1v.w;
                }
                const float si0 = wave_sum64((ai0.x + ai0.y) + (ai0.z + ai0.w));
                const float si1 = wave_sum64((ai1.x + ai1.y) + (ai1.z + ai1.w));
                const float si2 = wave_sum64((ai2.x + ai2.y) + (ai2.z + ai2.w));
                const float sh0 = wave_sum64((ah0.x + ah0.y) + (ah0.z + ah0.w));
                const float sh1 = wave_sum64((ah1.x + ah1.y) + (ah1.z + ah1.w));
                const float sh2 = wave_sum64((ah2.x + ah2.y) + (ah2.z + ah2.w));
                const float r = 1.f / (1.f + __expf(-(si0 + bi10 + sh0 + bh10)));
                const float z = 1.f / (1.f + __expf(-(si1 + bi11 + sh1 + bh11)));
                const float nn = tanhf(si2 + bi12 + r * (sh2 + bh12));
                const float hnew = (1.f - z) * nn + z * hprev1;
                hprev1 = hnew;
                if (e <= T + 1) {
                    if (lane == 0) {
                        const u64 v = ((u64)(unsigned)(e - 1) << 32) | (u64)__float_as_uint(hnew);
                        __hip_atomic_store(&hbuf1[((e - 1) & 1) * HID + d], v,
                                           __ATOMIC_RELAXED, __HIP_MEMORY_SCOPE_AGENT);
                    }
                } else {
                    if (lane == 0) hout[d] = hnew;   // e == T+2: final h1 = out1[T]
                }
            }
            // delay h0 snapshot by one epoch for next D
            #pragma unroll
            for (int j = 0; j < 4; j++) hr0_prev[j] = hr0[j];
        }
    }
}

// ---------------------------------------------------------------------------
// out[o] = dot(fc_W[o,:], h) + fc_b[o]; 64 waves, 16 outputs each.
// ---------------------------------------------------------------------------
__global__ __launch_bounds__(256) void fc_kernel(
    const float* __restrict__ h, const float* __restrict__ W,
    const float* __restrict__ b, float* __restrict__ out)
{
    __shared__ float hs[HID];
    const int wv = blockIdx.x * 4 + (threadIdx.x >> 6);
    const int lane = threadIdx.x & 63;
    for (int i = threadIdx.x; i < HID; i += 256) hs[i] = h[i];
    __syncthreads();
    for (int o = wv * 16; o < wv * 16 + 16; o++) {
        float acc = 0.f;
        #pragma unroll
        for (int u = 0; u < 16; u++)
            acc += W[(size_t)o * HID + lane + 64 * u] * hs[lane + 64 * u];
        #pragma unroll
        for (int off = 32; off; off >>= 1)
            acc += __shfl_down(acc, off, 64);
        if (lane == 0) out[o] = acc + b[o];
    }
}

// ---------------------------------------------------------------------------
extern "C" void kernel_launch(void* const* d_in, const int* in_sizes, int n_in,
                              void* d_out, int out_size, void* d_ws, size_t ws_size,
                              hipStream_t stream)
{
    const float* node_feats = (const float*)d_in[0];
    const int*   node_types = (const int*)d_in[1];
    const float* W1   = (const float*)d_in[2];
    const float* b1   = (const float*)d_in[3];
    const float* W2   = (const float*)d_in[4];
    const float* b2   = (const float*)d_in[5];
    const float* Wih0 = (const float*)d_in[6];
    const float* Whh0 = (const float*)d_in[7];
    const float* bih0 = (const float*)d_in[8];
    const float* bhh0 = (const float*)d_in[9];
    const float* Wih1 = (const float*)d_in[10];
    const float* Whh1 = (const float*)d_in[11];
    const float* bih1 = (const float*)d_in[12];
    const float* bhh1 = (const float*)d_in[13];
    const float* h_init = (const float*)d_in[14];
    const float* fc_W = (const float*)d_in[15];
    const float* fc_b = (const float*)d_in[16];
    float* out = (float*)d_out;

    char* ws = (char*)d_ws;
    const size_t GI_OFF    = 0;                      // 8192*3072*4 = 100663296
    const size_t EMB_OFF   = 100663296;              // 8192*512*4  = 16777216
    const size_t HOUT_OFF  = 117440512;              // 1024*4      = 4096
    const size_t HBUF0_OFF = 117444608;              // 2048*8      = 16384
    const size_t HBUF1_OFF = 117460992;              // 2048*8      = 16384

    float* gi   = (float*)(ws + GI_OFF);
    float* emb  = (float*)(ws + EMB_OFF);
    float* hout = (float*)(ws + HOUT_OFF);
    u64* hbuf0  = (u64*)(ws + HBUF0_OFF);
    u64* hbuf1  = (u64*)(ws + HBUF1_OFF);
    // hbufs start 0xAA-poisoned: tag 0xAAAAAAAA never matches an epoch in
    // [1, 8194], so no memset needed anywhere.

    // 1. Expert MLP -> emb [8192, 512]
    mlp_kernel<<<N_NODES, 256, 0, stream>>>(node_feats, node_types, W1, b1, W2, b2, emb);

    // 2. gi0 = emb @ Wih0^T + bih0  [8192, 3072]
    gemm_bt_bias<<<dim3(G3 / BN, N_NODES / BM), 256, 0, stream>>>(
        emb, Wih0, bih0, gi, N_NODES, G3, EMB);

    // 3. fused 2-layer scan (dual-engine offset, DPP reduce, weights in VGPR,
    //    single-barrier epochs + visibility-tuned poll)
    gru_fused<<<256, 512, 0, stream>>>(gi, Whh0, bhh0, Wih1, bih1, Whh1, bhh1,
                                       h_init, hbuf0, hbuf1, hout, SEQ);

    // 4. FC on final hidden state
    fc_kernel<<<16, 256, 0, stream>>>(hout, fc_W, fc_b, out);
}